// Round 4
// baseline (551.302 us; speedup 1.0000x reference)
//
#include <hip/hip_runtime.h>
#include <cstdint>

#define NN   4096
#define EMB  16
#define CIN  64
#define COUT 64
#define BB   16

typedef __attribute__((ext_vector_type(8))) short short8v;
typedef __attribute__((ext_vector_type(4))) float f32x4;

__device__ inline ushort f2bf(float f) {
    uint32_t u = __builtin_bit_cast(uint32_t, f);
    uint32_t r = (u + 0x7FFFu + ((u >> 16) & 1u)) >> 16;
    return (ushort)r;
}

// ---------------------------------------------------------------------------
// Kernel 1: A = softmax(relu(E @ E^T), axis=1), stored bf16. One block/row.
// ---------------------------------------------------------------------------
__global__ __launch_bounds__(256) void adj_softmax_kernel(
    const float* __restrict__ E, ushort* __restrict__ A)
{
    const int n = blockIdx.x;
    const int t = threadIdx.x;
    __shared__ float en[EMB];
    __shared__ float red[4];

    if (t < EMB) en[t] = E[(size_t)n * EMB + t];
    __syncthreads();

    float v[16];
    float mx = 0.0f;  // relu >= 0
    #pragma unroll
    for (int r = 0; r < 16; ++r) {
        int m = t + r * 256;
        const float4* ep = reinterpret_cast<const float4*>(E + (size_t)m * EMB);
        float4 e0 = ep[0], e1 = ep[1], e2 = ep[2], e3 = ep[3];
        float d = e0.x*en[0] + e0.y*en[1] + e0.z*en[2]  + e0.w*en[3]
                + e1.x*en[4] + e1.y*en[5] + e1.z*en[6]  + e1.w*en[7]
                + e2.x*en[8] + e2.y*en[9] + e2.z*en[10] + e2.w*en[11]
                + e3.x*en[12]+ e3.y*en[13]+ e3.z*en[14] + e3.w*en[15];
        d = fmaxf(d, 0.0f);
        v[r] = d;
        mx = fmaxf(mx, d);
    }
    #pragma unroll
    for (int off = 32; off > 0; off >>= 1) mx = fmaxf(mx, __shfl_xor(mx, off, 64));
    if ((t & 63) == 0) red[t >> 6] = mx;
    __syncthreads();
    mx = fmaxf(fmaxf(red[0], red[1]), fmaxf(red[2], red[3]));
    __syncthreads();

    float s = 0.0f;
    #pragma unroll
    for (int r = 0; r < 16; ++r) { v[r] = __expf(v[r] - mx); s += v[r]; }
    #pragma unroll
    for (int off = 32; off > 0; off >>= 1) s += __shfl_xor(s, off, 64);
    if ((t & 63) == 0) red[t >> 6] = s;
    __syncthreads();
    float inv = 1.0f / (red[0] + red[1] + red[2] + red[3]);

    #pragma unroll
    for (int r = 0; r < 16; ++r)
        A[(size_t)n * NN + t + r * 256] = f2bf(v[r] * inv);
}

// ---------------------------------------------------------------------------
// Kernel 2: XT[b][c][m] (bf16) = X[b][m][c] (f32) — transpose + convert.
// ---------------------------------------------------------------------------
__global__ __launch_bounds__(256) void transpose_conv_kernel(
    const float* __restrict__ X, ushort* __restrict__ XT)
{
    const int m0 = blockIdx.x * 64;
    const int b  = blockIdx.y;
    const int t  = threadIdx.x;
    __shared__ float tile[64][68];
    const float* Xb = X + (size_t)b * NN * CIN;

    #pragma unroll
    for (int it = 0; it < 4; ++it) {
        int r  = (t >> 4) + it * 16;
        int c4 = (t & 15) * 4;
        float4 v = *reinterpret_cast<const float4*>(Xb + (size_t)(m0 + r) * CIN + c4);
        *reinterpret_cast<float4*>(&tile[r][c4]) = v;
    }
    __syncthreads();
    #pragma unroll
    for (int it = 0; it < 2; ++it) {
        int c  = (t >> 3) + it * 32;
        int k8 = (t & 7) * 8;
        ushort4 p0, p1;
        p0.x = f2bf(tile[k8+0][c]); p0.y = f2bf(tile[k8+1][c]);
        p0.z = f2bf(tile[k8+2][c]); p0.w = f2bf(tile[k8+3][c]);
        p1.x = f2bf(tile[k8+4][c]); p1.y = f2bf(tile[k8+5][c]);
        p1.z = f2bf(tile[k8+6][c]); p1.w = f2bf(tile[k8+7][c]);
        ushort* dst = XT + ((size_t)b * CIN + c) * NN + m0 + k8;
        *reinterpret_cast<ushort4*>(dst)     = p0;
        *reinterpret_cast<ushort4*>(dst + 4) = p1;
    }
}

// ---------------------------------------------------------------------------
// Kernel 3: wpT[d][o][ki] (bf16) = wp[d][ki][o] (f32).  grid 64 x 256.
// ---------------------------------------------------------------------------
__global__ __launch_bounds__(256) void wp_pack_kernel(
    const float* __restrict__ wp, ushort* __restrict__ wpT)
{
    const int d  = blockIdx.x >> 2;
    const int q  = blockIdx.x & 3;
    const int o  = q * 16 + (threadIdx.x >> 4);
    const int k0 = (threadIdx.x & 15) * 12;
    const float* src = wp + (size_t)d * 12288 + o;
    ushort* dst = wpT + ((size_t)d * 64 + o) * 192 + k0;
    #pragma unroll
    for (int j = 0; j < 12; ++j) dst[j] = f2bf(src[(size_t)(k0 + j) * 64]);
}

// ---------------------------------------------------------------------------
// Kernel 4/5: MFMA GEMM, 2-phase double-buffered (T3-min).
// Yt[b][c][m] = bf16( alpha * sum_k A[m,k]*BT[b,c,k] (- Xsub[b,m,c]) )
// BM=128, BN=64, BK=64, 4 waves, wave = 32x64 of 16x16x32 frags.
// LDS rows padded to 66 shorts (132B = 33 banks): write banks (r+4c),
// frag-read banks rl+const -> ~conflict-free (the 72-pad was 8-way on writes).
// One barrier per K-step; next tile's global loads issued before compute.
// ---------------------------------------------------------------------------
__global__ __launch_bounds__(256) void gemm_mfma_kernel(
    const ushort* __restrict__ A, const ushort* __restrict__ BT,
    const float* __restrict__ Xsub, ushort* __restrict__ Yt, float alpha)
{
    __shared__ ushort Alds[2][128][66];
    __shared__ ushort Blds[2][64][66];

    const int i = blockIdx.x;                        // 0..511
    const int m_tile = (i & 7) * 4 + ((i >> 3) & 3); // all 16 b of an m_tile -> same XCD
    const int b = i >> 5;
    const int n0 = m_tile * 128;
    const int t = threadIdx.x;
    const int w = t >> 6;
    const int l = t & 63;

    const ushort* Ab = A  + (size_t)n0 * NN;
    const ushort* Bb = BT + (size_t)b * CIN * NN;

    const int arow = t >> 3;         // 0..31
    const int acol = (t & 7) * 8;    // k-element offset
    const int xc   = t >> 2;         // 0..63
    const int xk   = (t & 3) * 16;

    const ushort* aptr = Ab + (size_t)arow * NN + acol;
    const ushort* bptr = Bb + (size_t)xc * NN + xk;

    uint4 areg[4], breg[2];

    f32x4 acc[2][4];
    #pragma unroll
    for (int mi = 0; mi < 2; ++mi)
        #pragma unroll
        for (int ni = 0; ni < 4; ++ni)
            acc[mi][ni] = (f32x4){0.f, 0.f, 0.f, 0.f};

    // prologue: stage tile 0
    #pragma unroll
    for (int it = 0; it < 4; ++it)
        areg[it] = *reinterpret_cast<const uint4*>(aptr + (size_t)it * 32 * NN);
    breg[0] = *reinterpret_cast<const uint4*>(bptr);
    breg[1] = *reinterpret_cast<const uint4*>(bptr + 8);
    #pragma unroll
    for (int it = 0; it < 4; ++it)
        *reinterpret_cast<uint4*>(&Alds[0][arow + it * 32][acol]) = areg[it];
    *reinterpret_cast<uint4*>(&Blds[0][xc][xk])     = breg[0];
    *reinterpret_cast<uint4*>(&Blds[0][xc][xk + 8]) = breg[1];

    const int rl = l & 15;
    int cur = 0;
    const int NT = NN / 64;

    for (int kti = 0; kti < NT; ++kti) {
        const bool more = (kti + 1 < NT);
        if (more) {
            const int kn = (kti + 1) * 64;
            #pragma unroll
            for (int it = 0; it < 4; ++it)
                areg[it] = *reinterpret_cast<const uint4*>(aptr + (size_t)it * 32 * NN + kn);
            breg[0] = *reinterpret_cast<const uint4*>(bptr + kn);
            breg[1] = *reinterpret_cast<const uint4*>(bptr + kn + 8);
        }
        __syncthreads();   // buf[cur] writes visible; prior readers of buf[cur^1] done

        #pragma unroll
        for (int ks = 0; ks < 64; ks += 32) {
            const int koff = ks + (l >> 4) * 8;
            short8v af[2], bfr[4];
            #pragma unroll
            for (int mi = 0; mi < 2; ++mi)
                af[mi] = *reinterpret_cast<const short8v*>(
                    &Alds[cur][w * 32 + mi * 16 + rl][koff]);
            #pragma unroll
            for (int ni = 0; ni < 4; ++ni)
                bfr[ni] = *reinterpret_cast<const short8v*>(
                    &Blds[cur][ni * 16 + rl][koff]);
            #pragma unroll
            for (int mi = 0; mi < 2; ++mi)
                #pragma unroll
                for (int ni = 0; ni < 4; ++ni)
                    acc[mi][ni] = __builtin_amdgcn_mfma_f32_16x16x32_bf16(
                        af[mi], bfr[ni], acc[mi][ni], 0, 0, 0);
        }

        if (more) {
            #pragma unroll
            for (int it = 0; it < 4; ++it)
                *reinterpret_cast<uint4*>(&Alds[cur ^ 1][arow + it * 32][acol]) = areg[it];
            *reinterpret_cast<uint4*>(&Blds[cur ^ 1][xc][xk])     = breg[0];
            *reinterpret_cast<uint4*>(&Blds[cur ^ 1][xc][xk + 8]) = breg[1];
        }
        cur ^= 1;
    }

    // Epilogue: C/D layout col=lane&15, row=(lane>>4)*4+reg
    const int rquad = (l >> 4) * 4;
    #pragma unroll
    for (int mi = 0; mi < 2; ++mi) {
        int row0 = w * 32 + mi * 16 + rquad;
        #pragma unroll
        for (int ni = 0; ni < 4; ++ni) {
            int c = ni * 16 + rl;
            ushort4 pk;
            #pragma unroll
            for (int j = 0; j < 4; ++j) {
                int row = n0 + row0 + j;
                float vv = alpha * acc[mi][ni][j];
                if (Xsub) vv -= Xsub[((size_t)b * NN + row) * CIN + c];
                ((ushort*)&pk)[j] = f2bf(vv);
            }
            *reinterpret_cast<ushort4*>(
                Yt + ((size_t)b * CIN + c) * NN + n0 + row0) = pk;
        }
    }
}

// ---------------------------------------------------------------------------
// Kernel 6: apply.  out[b,n,o] = sum_d E[n,d]*( XG[b,n,:]@wpT[d] + bp[d,o] )
// ---------------------------------------------------------------------------
__global__ __launch_bounds__(256) void apply_kernel(
    const ushort* __restrict__ XT, const ushort* __restrict__ Y1T,
    const ushort* __restrict__ Y2T, const ushort* __restrict__ wpT,
    const float* __restrict__ E, const float* __restrict__ bp,
    float* __restrict__ out)
{
    __shared__ ushort Alds[64][200];
    __shared__ ushort Wlds[64][200];
    __shared__ float  Elds[64][17];
    __shared__ float  bplds[16 * 64];

    const int r0 = blockIdx.x * 64;
    const int b  = r0 >> 12;
    const int n0 = r0 & (NN - 1);
    const int t  = threadIdx.x;
    const int w  = t >> 6;
    const int l  = t & 63;

    {
        float4 ev = *reinterpret_cast<const float4*>(E + (size_t)n0 * EMB + t * 4);
        int rr = t >> 2, dd = (t & 3) * 4;
        Elds[rr][dd + 0] = ev.x; Elds[rr][dd + 1] = ev.y;
        Elds[rr][dd + 2] = ev.z; Elds[rr][dd + 3] = ev.w;
        float4 bv = *reinterpret_cast<const float4*>(bp + t * 4);
        *reinterpret_cast<float4*>(&bplds[t * 4]) = bv;
    }
    {
        const int c  = t >> 2;
        const int mg = (t & 3) * 16;
        const size_t base = ((size_t)b * CIN + c) * NN + n0 + mg;
        const ushort* __restrict__ srcs[3] = {XT, Y1T, Y2T};
        #pragma unroll
        for (int ks = 0; ks < 3; ++ks) {
            short8v v0 = *reinterpret_cast<const short8v*>(srcs[ks] + base);
            short8v v1 = *reinterpret_cast<const short8v*>(srcs[ks] + base + 8);
            #pragma unroll
            for (int j = 0; j < 8; ++j) Alds[mg + j][ks * 64 + c] = (ushort)v0[j];
            #pragma unroll
            for (int j = 0; j < 8; ++j) Alds[mg + 8 + j][ks * 64 + c] = (ushort)v1[j];
        }
    }
    __syncthreads();

    const int rl = l & 15;
    const int kq = (l >> 4) * 8;

    short8v af[6];
    #pragma unroll
    for (int ks = 0; ks < 6; ++ks)
        af[ks] = *reinterpret_cast<const short8v*>(&Alds[w * 16 + rl][ks * 32 + kq]);

    f32x4 mainacc[4];
    #pragma unroll
    for (int ni = 0; ni < 4; ++ni) mainacc[ni] = (f32x4){0.f, 0.f, 0.f, 0.f};

    const int wo = t >> 2;
    const int wk = (t & 3) * 48;

    for (int d = 0; d < EMB; ++d) {
        __syncthreads();
        {
            const ushort* src = wpT + ((size_t)(d * 64 + wo)) * 192 + wk;
            #pragma unroll
            for (int j = 0; j < 6; ++j) {
                short8v v = *reinterpret_cast<const short8v*>(src + j * 8);
                *reinterpret_cast<short8v*>(&Wlds[wo][wk + j * 8]) = v;
            }
        }
        __syncthreads();

        f32x4 tmp[4];
        #pragma unroll
        for (int ni = 0; ni < 4; ++ni) tmp[ni] = (f32x4){0.f, 0.f, 0.f, 0.f};
        #pragma unroll
        for (int ks = 0; ks < 6; ++ks) {
            #pragma unroll
            for (int ni = 0; ni < 4; ++ni) {
                short8v bfr = *reinterpret_cast<const short8v*>(
                    &Wlds[ni * 16 + rl][ks * 32 + kq]);
                tmp[ni] = __builtin_amdgcn_mfma_f32_16x16x32_bf16(
                    af[ks], bfr, tmp[ni], 0, 0, 0);
            }
        }
        float e[4];
        #pragma unroll
        for (int j = 0; j < 4; ++j) e[j] = Elds[w * 16 + (l >> 4) * 4 + j][d];
        #pragma unroll
        for (int ni = 0; ni < 4; ++ni)
            #pragma unroll
            for (int j = 0; j < 4; ++j)
                mainacc[ni][j] += e[j] * tmp[ni][j];
    }

    const int lr4 = (l >> 4) * 4;
    #pragma unroll
    for (int ni = 0; ni < 4; ++ni) {
        int col = ni * 16 + rl;
        #pragma unroll
        for (int j = 0; j < 4; ++j) {
            int locrow = w * 16 + lr4 + j;
            float bias = 0.0f;
            #pragma unroll
            for (int d = 0; d < EMB; ++d)
                bias += Elds[locrow][d] * bplds[d * 64 + col];
            out[((size_t)b * NN + n0 + locrow) * COUT + col] = mainacc[ni][j] + bias;
        }
    }
}

// ---------------------------------------------------------------------------
extern "C" void kernel_launch(void* const* d_in, const int* in_sizes, int n_in,
                              void* d_out, int out_size, void* d_ws, size_t ws_size,
                              hipStream_t stream)
{
    const float* X  = (const float*)d_in[0];  // [16,4096,64]
    const float* E  = (const float*)d_in[1];  // [4096,16]
    const float* wp = (const float*)d_in[2];  // [16,3,64,64]
    const float* bp = (const float*)d_in[3];  // [16,64]
    float* out = (float*)d_out;

    char* ws = (char*)d_ws;
    size_t off = 0;
    ushort* Abf = (ushort*)(ws + off); off += (size_t)NN * NN * 2;        // 32 MB
    ushort* XT  = (ushort*)(ws + off); off += (size_t)BB * CIN * NN * 2;  //  8 MB
    ushort* Y1T = (ushort*)(ws + off); off += (size_t)BB * CIN * NN * 2;  //  8 MB
    ushort* Y2T = (ushort*)(ws + off); off += (size_t)BB * CIN * NN * 2;  //  8 MB
    ushort* wpT = (ushort*)(ws + off);                                    // 384 KB

    adj_softmax_kernel   <<<NN, 256, 0, stream>>>(E, Abf);
    transpose_conv_kernel<<<dim3(NN / 64, BB), 256, 0, stream>>>(X, XT);
    wp_pack_kernel       <<<64, 256, 0, stream>>>(wp, wpT);
    gemm_mfma_kernel     <<<512, 256, 0, stream>>>(Abf, XT,  nullptr, Y1T, 1.0f);
    gemm_mfma_kernel     <<<512, 256, 0, stream>>>(Abf, Y1T, X,       Y2T, 2.0f);
    apply_kernel         <<<1024, 256, 0, stream>>>(XT, Y1T, Y2T, wpT, E, bp, out);
}

// Round 5
// 386.993 us; speedup vs baseline: 1.4246x; 1.4246x over previous
//
#include <hip/hip_runtime.h>
#include <cstdint>

#define NN   4096
#define EMB  16
#define CIN  64
#define COUT 64
#define BB   16

typedef __attribute__((ext_vector_type(8))) short short8v;
typedef __attribute__((ext_vector_type(4))) float f32x4;

__device__ inline ushort f2bf(float f) {
    uint32_t u = __builtin_bit_cast(uint32_t, f);
    uint32_t r = (u + 0x7FFFu + ((u >> 16) & 1u)) >> 16;
    return (ushort)r;
}

// ---------------------------------------------------------------------------
// Kernel 1: A = softmax(relu(E @ E^T), axis=1), stored bf16. One block/row.
// ---------------------------------------------------------------------------
__global__ __launch_bounds__(256) void adj_softmax_kernel(
    const float* __restrict__ E, ushort* __restrict__ A)
{
    const int n = blockIdx.x;
    const int t = threadIdx.x;
    __shared__ float en[EMB];
    __shared__ float red[4];

    if (t < EMB) en[t] = E[(size_t)n * EMB + t];
    __syncthreads();

    float v[16];
    float mx = 0.0f;  // relu >= 0
    #pragma unroll
    for (int r = 0; r < 16; ++r) {
        int m = t + r * 256;
        const float4* ep = reinterpret_cast<const float4*>(E + (size_t)m * EMB);
        float4 e0 = ep[0], e1 = ep[1], e2 = ep[2], e3 = ep[3];
        float d = e0.x*en[0] + e0.y*en[1] + e0.z*en[2]  + e0.w*en[3]
                + e1.x*en[4] + e1.y*en[5] + e1.z*en[6]  + e1.w*en[7]
                + e2.x*en[8] + e2.y*en[9] + e2.z*en[10] + e2.w*en[11]
                + e3.x*en[12]+ e3.y*en[13]+ e3.z*en[14] + e3.w*en[15];
        d = fmaxf(d, 0.0f);
        v[r] = d;
        mx = fmaxf(mx, d);
    }
    #pragma unroll
    for (int off = 32; off > 0; off >>= 1) mx = fmaxf(mx, __shfl_xor(mx, off, 64));
    if ((t & 63) == 0) red[t >> 6] = mx;
    __syncthreads();
    mx = fmaxf(fmaxf(red[0], red[1]), fmaxf(red[2], red[3]));
    __syncthreads();

    float s = 0.0f;
    #pragma unroll
    for (int r = 0; r < 16; ++r) { v[r] = __expf(v[r] - mx); s += v[r]; }
    #pragma unroll
    for (int off = 32; off > 0; off >>= 1) s += __shfl_xor(s, off, 64);
    if ((t & 63) == 0) red[t >> 6] = s;
    __syncthreads();
    float inv = 1.0f / (red[0] + red[1] + red[2] + red[3]);

    #pragma unroll
    for (int r = 0; r < 16; ++r)
        A[(size_t)n * NN + t + r * 256] = f2bf(v[r] * inv);
}

// ---------------------------------------------------------------------------
// Kernel 2: XT[b][c][m] (bf16) = X[b][m][c] (f32) — transpose + convert.
// ---------------------------------------------------------------------------
__global__ __launch_bounds__(256) void transpose_conv_kernel(
    const float* __restrict__ X, ushort* __restrict__ XT)
{
    const int m0 = blockIdx.x * 64;
    const int b  = blockIdx.y;
    const int t  = threadIdx.x;
    __shared__ float tile[64][68];
    const float* Xb = X + (size_t)b * NN * CIN;

    #pragma unroll
    for (int it = 0; it < 4; ++it) {
        int r  = (t >> 4) + it * 16;
        int c4 = (t & 15) * 4;
        float4 v = *reinterpret_cast<const float4*>(Xb + (size_t)(m0 + r) * CIN + c4);
        *reinterpret_cast<float4*>(&tile[r][c4]) = v;
    }
    __syncthreads();
    #pragma unroll
    for (int it = 0; it < 2; ++it) {
        int c  = (t >> 3) + it * 32;
        int k8 = (t & 7) * 8;
        ushort4 p0, p1;
        p0.x = f2bf(tile[k8+0][c]); p0.y = f2bf(tile[k8+1][c]);
        p0.z = f2bf(tile[k8+2][c]); p0.w = f2bf(tile[k8+3][c]);
        p1.x = f2bf(tile[k8+4][c]); p1.y = f2bf(tile[k8+5][c]);
        p1.z = f2bf(tile[k8+6][c]); p1.w = f2bf(tile[k8+7][c]);
        ushort* dst = XT + ((size_t)b * CIN + c) * NN + m0 + k8;
        *reinterpret_cast<ushort4*>(dst)     = p0;
        *reinterpret_cast<ushort4*>(dst + 4) = p1;
    }
}

// ---------------------------------------------------------------------------
// Kernel 3: wpT[d][o][ki] (bf16) = wp[d][ki][o] (f32).  grid 64 x 256.
// ---------------------------------------------------------------------------
__global__ __launch_bounds__(256) void wp_pack_kernel(
    const float* __restrict__ wp, ushort* __restrict__ wpT)
{
    const int d  = blockIdx.x >> 2;
    const int q  = blockIdx.x & 3;
    const int o  = q * 16 + (threadIdx.x >> 4);
    const int k0 = (threadIdx.x & 15) * 12;
    const float* src = wp + (size_t)d * 12288 + o;
    ushort* dst = wpT + ((size_t)d * 64 + o) * 192 + k0;
    #pragma unroll
    for (int j = 0; j < 12; ++j) dst[j] = f2bf(src[(size_t)(k0 + j) * 64]);
}

// ---------------------------------------------------------------------------
// Kernel 4/5: MFMA GEMM, 2-phase double-buffered, reg-staged.
// Yt[b][c][m] = bf16( alpha * sum_k A[m,k]*BT[b,c,k] (- Xsub[b,m,c]) )
// BM=128, BN=64, BK=64, 4 waves, wave = 32x64 of 16x16x32 frags.
// LDS row stride 72 shorts = 144 B: 16B-ALIGNED (the round-4 regression was
// stride 66 = 132 B breaking uint4 alignment), 9 bank-quads -> reads/writes
// spread (r+chunk) mod 8 -> ~2-way (free).
// Pipeline: load tile k+1 to regs BEFORE computing tile k; ds_write after
// compute into the other buffer; one barrier per K-step.
// ---------------------------------------------------------------------------
__global__ __launch_bounds__(256) void gemm_mfma_kernel(
    const ushort* __restrict__ A, const ushort* __restrict__ BT,
    const float* __restrict__ Xsub, ushort* __restrict__ Yt, float alpha)
{
    __shared__ ushort Alds[2][128][72];
    __shared__ ushort Blds[2][64][72];

    const int i = blockIdx.x;                        // 0..511
    const int m_tile = (i & 7) * 4 + ((i >> 3) & 3); // all 16 b of an m_tile -> same XCD
    const int b = i >> 5;
    const int n0 = m_tile * 128;
    const int t = threadIdx.x;
    const int w = t >> 6;
    const int l = t & 63;

    const ushort* Ab = A  + (size_t)n0 * NN;
    const ushort* Bb = BT + (size_t)b * CIN * NN;

    const int arow = t >> 3;         // 0..31
    const int acol = (t & 7) * 8;    // k-element offset (16B-aligned in row)
    const int xc   = t >> 2;         // 0..63
    const int xk   = (t & 3) * 16;

    const ushort* aptr = Ab + (size_t)arow * NN + acol;
    const ushort* bptr = Bb + (size_t)xc * NN + xk;

    uint4 areg[4], breg[2];

    f32x4 acc[2][4];
    #pragma unroll
    for (int mi = 0; mi < 2; ++mi)
        #pragma unroll
        for (int ni = 0; ni < 4; ++ni)
            acc[mi][ni] = (f32x4){0.f, 0.f, 0.f, 0.f};

    // prologue: stage tile 0
    #pragma unroll
    for (int it = 0; it < 4; ++it)
        areg[it] = *reinterpret_cast<const uint4*>(aptr + (size_t)it * 32 * NN);
    breg[0] = *reinterpret_cast<const uint4*>(bptr);
    breg[1] = *reinterpret_cast<const uint4*>(bptr + 8);
    #pragma unroll
    for (int it = 0; it < 4; ++it)
        *reinterpret_cast<uint4*>(&Alds[0][arow + it * 32][acol]) = areg[it];
    *reinterpret_cast<uint4*>(&Blds[0][xc][xk])     = breg[0];
    *reinterpret_cast<uint4*>(&Blds[0][xc][xk + 8]) = breg[1];

    const int rl = l & 15;
    int cur = 0;
    const int NT = NN / 64;

    for (int kti = 0; kti < NT; ++kti) {
        const bool more = (kti + 1 < NT);
        if (more) {
            const int kn = (kti + 1) * 64;
            #pragma unroll
            for (int it = 0; it < 4; ++it)
                areg[it] = *reinterpret_cast<const uint4*>(aptr + (size_t)it * 32 * NN + kn);
            breg[0] = *reinterpret_cast<const uint4*>(bptr + kn);
            breg[1] = *reinterpret_cast<const uint4*>(bptr + kn + 8);
        }
        __syncthreads();   // buf[cur] writes visible; prior readers of buf[cur^1] done

        #pragma unroll
        for (int ks = 0; ks < 64; ks += 32) {
            const int koff = ks + (l >> 4) * 8;
            short8v af[2], bfr[4];
            #pragma unroll
            for (int mi = 0; mi < 2; ++mi)
                af[mi] = *reinterpret_cast<const short8v*>(
                    &Alds[cur][w * 32 + mi * 16 + rl][koff]);
            #pragma unroll
            for (int ni = 0; ni < 4; ++ni)
                bfr[ni] = *reinterpret_cast<const short8v*>(
                    &Blds[cur][ni * 16 + rl][koff]);
            #pragma unroll
            for (int mi = 0; mi < 2; ++mi)
                #pragma unroll
                for (int ni = 0; ni < 4; ++ni)
                    acc[mi][ni] = __builtin_amdgcn_mfma_f32_16x16x32_bf16(
                        af[mi], bfr[ni], acc[mi][ni], 0, 0, 0);
        }

        if (more) {
            #pragma unroll
            for (int it = 0; it < 4; ++it)
                *reinterpret_cast<uint4*>(&Alds[cur ^ 1][arow + it * 32][acol]) = areg[it];
            *reinterpret_cast<uint4*>(&Blds[cur ^ 1][xc][xk])     = breg[0];
            *reinterpret_cast<uint4*>(&Blds[cur ^ 1][xc][xk + 8]) = breg[1];
        }
        cur ^= 1;
    }

    // Epilogue: C/D layout col=lane&15, row=(lane>>4)*4+reg
    const int rquad = (l >> 4) * 4;
    #pragma unroll
    for (int mi = 0; mi < 2; ++mi) {
        int row0 = w * 32 + mi * 16 + rquad;
        #pragma unroll
        for (int ni = 0; ni < 4; ++ni) {
            int c = ni * 16 + rl;
            ushort4 pk;
            #pragma unroll
            for (int j = 0; j < 4; ++j) {
                int row = n0 + row0 + j;
                float vv = alpha * acc[mi][ni][j];
                if (Xsub) vv -= Xsub[((size_t)b * NN + row) * CIN + c];
                ((ushort*)&pk)[j] = f2bf(vv);
            }
            *reinterpret_cast<ushort4*>(
                Yt + ((size_t)b * CIN + c) * NN + n0 + row0) = pk;
        }
    }
}

// ---------------------------------------------------------------------------
// Kernel 6: apply.  out[b,n,o] = sum_d E[n,d]*( XG[b,n,:]@wpT[d] + bp[d,o] )
// ---------------------------------------------------------------------------
__global__ __launch_bounds__(256) void apply_kernel(
    const ushort* __restrict__ XT, const ushort* __restrict__ Y1T,
    const ushort* __restrict__ Y2T, const ushort* __restrict__ wpT,
    const float* __restrict__ E, const float* __restrict__ bp,
    float* __restrict__ out)
{
    __shared__ ushort Alds[64][200];
    __shared__ ushort Wlds[64][200];
    __shared__ float  Elds[64][17];
    __shared__ float  bplds[16 * 64];

    const int r0 = blockIdx.x * 64;
    const int b  = r0 >> 12;
    const int n0 = r0 & (NN - 1);
    const int t  = threadIdx.x;
    const int w  = t >> 6;
    const int l  = t & 63;

    {
        float4 ev = *reinterpret_cast<const float4*>(E + (size_t)n0 * EMB + t * 4);
        int rr = t >> 2, dd = (t & 3) * 4;
        Elds[rr][dd + 0] = ev.x; Elds[rr][dd + 1] = ev.y;
        Elds[rr][dd + 2] = ev.z; Elds[rr][dd + 3] = ev.w;
        float4 bv = *reinterpret_cast<const float4*>(bp + t * 4);
        *reinterpret_cast<float4*>(&bplds[t * 4]) = bv;
    }
    {
        const int c  = t >> 2;
        const int mg = (t & 3) * 16;
        const size_t base = ((size_t)b * CIN + c) * NN + n0 + mg;
        const ushort* __restrict__ srcs[3] = {XT, Y1T, Y2T};
        #pragma unroll
        for (int ks = 0; ks < 3; ++ks) {
            short8v v0 = *reinterpret_cast<const short8v*>(srcs[ks] + base);
            short8v v1 = *reinterpret_cast<const short8v*>(srcs[ks] + base + 8);
            #pragma unroll
            for (int j = 0; j < 8; ++j) Alds[mg + j][ks * 64 + c] = (ushort)v0[j];
            #pragma unroll
            for (int j = 0; j < 8; ++j) Alds[mg + 8 + j][ks * 64 + c] = (ushort)v1[j];
        }
    }
    __syncthreads();

    const int rl = l & 15;
    const int kq = (l >> 4) * 8;

    short8v af[6];
    #pragma unroll
    for (int ks = 0; ks < 6; ++ks)
        af[ks] = *reinterpret_cast<const short8v*>(&Alds[w * 16 + rl][ks * 32 + kq]);

    f32x4 mainacc[4];
    #pragma unroll
    for (int ni = 0; ni < 4; ++ni) mainacc[ni] = (f32x4){0.f, 0.f, 0.f, 0.f};

    const int wo = t >> 2;
    const int wk = (t & 3) * 48;

    for (int d = 0; d < EMB; ++d) {
        __syncthreads();
        {
            const ushort* src = wpT + ((size_t)(d * 64 + wo)) * 192 + wk;
            #pragma unroll
            for (int j = 0; j < 6; ++j) {
                short8v v = *reinterpret_cast<const short8v*>(src + j * 8);
                *reinterpret_cast<short8v*>(&Wlds[wo][wk + j * 8]) = v;
            }
        }
        __syncthreads();

        f32x4 tmp[4];
        #pragma unroll
        for (int ni = 0; ni < 4; ++ni) tmp[ni] = (f32x4){0.f, 0.f, 0.f, 0.f};
        #pragma unroll
        for (int ks = 0; ks < 6; ++ks) {
            #pragma unroll
            for (int ni = 0; ni < 4; ++ni) {
                short8v bfr = *reinterpret_cast<const short8v*>(
                    &Wlds[ni * 16 + rl][ks * 32 + kq]);
                tmp[ni] = __builtin_amdgcn_mfma_f32_16x16x32_bf16(
                    af[ks], bfr, tmp[ni], 0, 0, 0);
            }
        }
        float e[4];
        #pragma unroll
        for (int j = 0; j < 4; ++j) e[j] = Elds[w * 16 + (l >> 4) * 4 + j][d];
        #pragma unroll
        for (int ni = 0; ni < 4; ++ni)
            #pragma unroll
            for (int j = 0; j < 4; ++j)
                mainacc[ni][j] += e[j] * tmp[ni][j];
    }

    const int lr4 = (l >> 4) * 4;
    #pragma unroll
    for (int ni = 0; ni < 4; ++ni) {
        int col = ni * 16 + rl;
        #pragma unroll
        for (int j = 0; j < 4; ++j) {
            int locrow = w * 16 + lr4 + j;
            float bias = 0.0f;
            #pragma unroll
            for (int d = 0; d < EMB; ++d)
                bias += Elds[locrow][d] * bplds[d * 64 + col];
            out[((size_t)b * NN + n0 + locrow) * COUT + col] = mainacc[ni][j] + bias;
        }
    }
}

// ---------------------------------------------------------------------------
extern "C" void kernel_launch(void* const* d_in, const int* in_sizes, int n_in,
                              void* d_out, int out_size, void* d_ws, size_t ws_size,
                              hipStream_t stream)
{
    const float* X  = (const float*)d_in[0];  // [16,4096,64]
    const float* E  = (const float*)d_in[1];  // [4096,16]
    const float* wp = (const float*)d_in[2];  // [16,3,64,64]
    const float* bp = (const float*)d_in[3];  // [16,64]
    float* out = (float*)d_out;

    char* ws = (char*)d_ws;
    size_t off = 0;
    ushort* Abf = (ushort*)(ws + off); off += (size_t)NN * NN * 2;        // 32 MB
    ushort* XT  = (ushort*)(ws + off); off += (size_t)BB * CIN * NN * 2;  //  8 MB
    ushort* Y1T = (ushort*)(ws + off); off += (size_t)BB * CIN * NN * 2;  //  8 MB
    ushort* Y2T = (ushort*)(ws + off); off += (size_t)BB * CIN * NN * 2;  //  8 MB
    ushort* wpT = (ushort*)(ws + off);                                    // 384 KB

    adj_softmax_kernel   <<<NN, 256, 0, stream>>>(E, Abf);
    transpose_conv_kernel<<<dim3(NN / 64, BB), 256, 0, stream>>>(X, XT);
    wp_pack_kernel       <<<64, 256, 0, stream>>>(wp, wpT);
    gemm_mfma_kernel     <<<512, 256, 0, stream>>>(Abf, XT,  nullptr, Y1T, 1.0f);
    gemm_mfma_kernel     <<<512, 256, 0, stream>>>(Abf, Y1T, X,       Y2T, 2.0f);
    apply_kernel         <<<1024, 256, 0, stream>>>(XT, Y1T, Y2T, wpT, E, bp, out);
}

// Round 6
// 301.131 us; speedup vs baseline: 1.8308x; 1.2851x over previous
//
#include <hip/hip_runtime.h>
#include <cstdint>

#define NN   4096
#define EMB  16
#define CIN  64
#define COUT 64
#define BB   16

typedef __attribute__((ext_vector_type(8))) short short8v;
typedef __attribute__((ext_vector_type(4))) float f32x4;

__device__ inline ushort f2bf(float f) {
    uint32_t u = __builtin_bit_cast(uint32_t, f);
    uint32_t r = (u + 0x7FFFu + ((u >> 16) & 1u)) >> 16;
    return (ushort)r;
}
__device__ inline float bf2f(ushort u) {
    uint32_t v = ((uint32_t)u) << 16;
    return __builtin_bit_cast(float, v);
}

// ---------------------------------------------------------------------------
// Kernel 1: A = softmax(relu(E @ E^T), axis=1), stored bf16. One block/row.
// ---------------------------------------------------------------------------
__global__ __launch_bounds__(256) void adj_softmax_kernel(
    const float* __restrict__ E, ushort* __restrict__ A)
{
    const int n = blockIdx.x;
    const int t = threadIdx.x;
    __shared__ float en[EMB];
    __shared__ float red[4];

    if (t < EMB) en[t] = E[(size_t)n * EMB + t];
    __syncthreads();

    float v[16];
    float mx = 0.0f;  // relu >= 0
    #pragma unroll
    for (int r = 0; r < 16; ++r) {
        int m = t + r * 256;
        const float4* ep = reinterpret_cast<const float4*>(E + (size_t)m * EMB);
        float4 e0 = ep[0], e1 = ep[1], e2 = ep[2], e3 = ep[3];
        float d = e0.x*en[0] + e0.y*en[1] + e0.z*en[2]  + e0.w*en[3]
                + e1.x*en[4] + e1.y*en[5] + e1.z*en[6]  + e1.w*en[7]
                + e2.x*en[8] + e2.y*en[9] + e2.z*en[10] + e2.w*en[11]
                + e3.x*en[12]+ e3.y*en[13]+ e3.z*en[14] + e3.w*en[15];
        d = fmaxf(d, 0.0f);
        v[r] = d;
        mx = fmaxf(mx, d);
    }
    #pragma unroll
    for (int off = 32; off > 0; off >>= 1) mx = fmaxf(mx, __shfl_xor(mx, off, 64));
    if ((t & 63) == 0) red[t >> 6] = mx;
    __syncthreads();
    mx = fmaxf(fmaxf(red[0], red[1]), fmaxf(red[2], red[3]));
    __syncthreads();

    float s = 0.0f;
    #pragma unroll
    for (int r = 0; r < 16; ++r) { v[r] = __expf(v[r] - mx); s += v[r]; }
    #pragma unroll
    for (int off = 32; off > 0; off >>= 1) s += __shfl_xor(s, off, 64);
    if ((t & 63) == 0) red[t >> 6] = s;
    __syncthreads();
    float inv = 1.0f / (red[0] + red[1] + red[2] + red[3]);

    #pragma unroll
    for (int r = 0; r < 16; ++r)
        A[(size_t)n * NN + t + r * 256] = f2bf(v[r] * inv);
}

// ---------------------------------------------------------------------------
// Kernel 2: XT[b][c][m] (bf16) = X[b][m][c] (f32) — transpose + convert.
// ---------------------------------------------------------------------------
__global__ __launch_bounds__(256) void transpose_conv_kernel(
    const float* __restrict__ X, ushort* __restrict__ XT)
{
    const int m0 = blockIdx.x * 64;
    const int b  = blockIdx.y;
    const int t  = threadIdx.x;
    __shared__ float tile[64][68];
    const float* Xb = X + (size_t)b * NN * CIN;

    #pragma unroll
    for (int it = 0; it < 4; ++it) {
        int r  = (t >> 4) + it * 16;
        int c4 = (t & 15) * 4;
        float4 v = *reinterpret_cast<const float4*>(Xb + (size_t)(m0 + r) * CIN + c4);
        *reinterpret_cast<float4*>(&tile[r][c4]) = v;
    }
    __syncthreads();
    #pragma unroll
    for (int it = 0; it < 2; ++it) {
        int c  = (t >> 3) + it * 32;
        int k8 = (t & 7) * 8;
        ushort4 p0, p1;
        p0.x = f2bf(tile[k8+0][c]); p0.y = f2bf(tile[k8+1][c]);
        p0.z = f2bf(tile[k8+2][c]); p0.w = f2bf(tile[k8+3][c]);
        p1.x = f2bf(tile[k8+4][c]); p1.y = f2bf(tile[k8+5][c]);
        p1.z = f2bf(tile[k8+6][c]); p1.w = f2bf(tile[k8+7][c]);
        ushort* dst = XT + ((size_t)b * CIN + c) * NN + m0 + k8;
        *reinterpret_cast<ushort4*>(dst)     = p0;
        *reinterpret_cast<ushort4*>(dst + 4) = p1;
    }
}

// ---------------------------------------------------------------------------
// Kernel 3: wpT[d][o][ki] (bf16) = wp[d][ki][o] (f32).  grid 64 x 256.
// ---------------------------------------------------------------------------
__global__ __launch_bounds__(256) void wp_pack_kernel(
    const float* __restrict__ wp, ushort* __restrict__ wpT)
{
    const int d  = blockIdx.x >> 2;
    const int q  = blockIdx.x & 3;
    const int o  = q * 16 + (threadIdx.x >> 4);
    const int k0 = (threadIdx.x & 15) * 12;
    const float* src = wp + (size_t)d * 12288 + o;
    ushort* dst = wpT + ((size_t)d * 64 + o) * 192 + k0;
    #pragma unroll
    for (int j = 0; j < 12; ++j) dst[j] = f2bf(src[(size_t)(k0 + j) * 64]);
}

// ---------------------------------------------------------------------------
// Kernel 4/5: MFMA GEMM, split-K x2 (occupancy: 512 -> 1024 blocks, 4/CU).
// part[(s*BB+b)*CIN+c][m] = sum_{k in slice s} A[m,k]*BT[b,c,k]   (f32)
// Round-3-proven single-buffer body: BM=128, BN=64, BK=64, 4 waves,
// wave = 32x64 of 16x16x32 frags, LDS stride 72 shorts (144 B, 16B-aligned).
// XCD swizzle: all 16 b and both k-slices of an m_tile share blockIdx%8.
// ---------------------------------------------------------------------------
__global__ __launch_bounds__(256) void gemm_mfma_splitk_kernel(
    const ushort* __restrict__ A, const ushort* __restrict__ BT,
    float* __restrict__ part)
{
    __shared__ ushort Alds[128][72];
    __shared__ ushort Blds[64][72];

    const int i = blockIdx.x;                        // 0..1023
    const int base = i & 511;
    const int s = i >> 9;                            // k-slice 0/1
    const int m_tile = (base & 7) * 4 + ((base >> 3) & 3);
    const int b = base >> 5;
    const int n0 = m_tile * 128;
    const int t = threadIdx.x;
    const int w = t >> 6;
    const int l = t & 63;

    const ushort* Ab = A  + (size_t)n0 * NN;
    const ushort* Bb = BT + (size_t)b * CIN * NN;

    f32x4 acc[2][4];
    #pragma unroll
    for (int mi = 0; mi < 2; ++mi)
        #pragma unroll
        for (int ni = 0; ni < 4; ++ni)
            acc[mi][ni] = (f32x4){0.f, 0.f, 0.f, 0.f};

    const int arow = t >> 3;         // 0..31
    const int acol = (t & 7) * 8;
    const int xc   = t >> 2;         // 0..63
    const int xk   = (t & 3) * 16;

    const int k0 = s * (NN / 2);
    for (int kt = k0; kt < k0 + NN / 2; kt += 64) {
        #pragma unroll
        for (int it = 0; it < 4; ++it) {
            int r = arow + it * 32;
            uint4 v = *reinterpret_cast<const uint4*>(Ab + (size_t)r * NN + kt + acol);
            *reinterpret_cast<uint4*>(&Alds[r][acol]) = v;
        }
        {
            const ushort* src = Bb + (size_t)xc * NN + kt + xk;
            uint4 v0 = *reinterpret_cast<const uint4*>(src);
            uint4 v1 = *reinterpret_cast<const uint4*>(src + 8);
            *reinterpret_cast<uint4*>(&Blds[xc][xk])     = v0;
            *reinterpret_cast<uint4*>(&Blds[xc][xk + 8]) = v1;
        }
        __syncthreads();

        const int rl = l & 15;
        #pragma unroll
        for (int ks = 0; ks < 64; ks += 32) {
            const int koff = ks + (l >> 4) * 8;
            short8v af[2], bfr[4];
            #pragma unroll
            for (int mi = 0; mi < 2; ++mi)
                af[mi] = *reinterpret_cast<const short8v*>(&Alds[w * 32 + mi * 16 + rl][koff]);
            #pragma unroll
            for (int ni = 0; ni < 4; ++ni)
                bfr[ni] = *reinterpret_cast<const short8v*>(&Blds[ni * 16 + rl][koff]);
            #pragma unroll
            for (int mi = 0; mi < 2; ++mi)
                #pragma unroll
                for (int ni = 0; ni < 4; ++ni)
                    acc[mi][ni] = __builtin_amdgcn_mfma_f32_16x16x32_bf16(
                        af[mi], bfr[ni], acc[mi][ni], 0, 0, 0);
        }
        __syncthreads();
    }

    // Epilogue: f32 partial, transposed layout part[(s*BB+b)*CIN+c][m].
    // C/D layout col=lane&15, row=(lane>>4)*4+reg -> 4 consecutive m per lane.
    const int rl = l & 15;
    const int rquad = (l >> 4) * 4;
    #pragma unroll
    for (int mi = 0; mi < 2; ++mi) {
        int row0 = w * 32 + mi * 16 + rquad;
        #pragma unroll
        for (int ni = 0; ni < 4; ++ni) {
            int c = ni * 16 + rl;
            float4 pk = make_float4(acc[mi][ni][0], acc[mi][ni][1],
                                    acc[mi][ni][2], acc[mi][ni][3]);
            *reinterpret_cast<float4*>(
                part + ((size_t)(s * BB + b) * CIN + c) * NN + n0 + row0) = pk;
        }
    }
}

// ---------------------------------------------------------------------------
// Kernel 6: combine split-K partials + epilogue.
// Yt[b][c][m] = f2bf( alpha*(p0+p1) - (dosub ? XT[b][c][m] : 0) )
// Flat over BB*CIN*NN elements; 8 per thread; fully coalesced.
// ---------------------------------------------------------------------------
__global__ __launch_bounds__(256) void combine_kernel(
    const float* __restrict__ part, const ushort* __restrict__ XT,
    ushort* __restrict__ Yt, float alpha, int dosub)
{
    const size_t idx = ((size_t)blockIdx.x * 256 + threadIdx.x) * 8;
    const size_t half = (size_t)BB * CIN * NN;
    float4 a0 = *reinterpret_cast<const float4*>(part + idx);
    float4 a1 = *reinterpret_cast<const float4*>(part + idx + 4);
    float4 b0 = *reinterpret_cast<const float4*>(part + half + idx);
    float4 b1 = *reinterpret_cast<const float4*>(part + half + idx + 4);
    float r[8] = { alpha*(a0.x+b0.x), alpha*(a0.y+b0.y),
                   alpha*(a0.z+b0.z), alpha*(a0.w+b0.w),
                   alpha*(a1.x+b1.x), alpha*(a1.y+b1.y),
                   alpha*(a1.z+b1.z), alpha*(a1.w+b1.w) };
    if (dosub) {
        short8v xv = *reinterpret_cast<const short8v*>(XT + idx);
        #pragma unroll
        for (int j = 0; j < 8; ++j) r[j] -= bf2f((ushort)xv[j]);
    }
    short8v o;
    #pragma unroll
    for (int j = 0; j < 8; ++j) o[j] = (short)f2bf(r[j]);
    *reinterpret_cast<short8v*>(Yt + idx) = o;
}

// ---------------------------------------------------------------------------
// Kernel 7: apply.  out[b,n,o] = sum_d E[n,d]*( XG[b,n,:]@wpT[d] + bp[d,o] )
// ---------------------------------------------------------------------------
__global__ __launch_bounds__(256) void apply_kernel(
    const ushort* __restrict__ XT, const ushort* __restrict__ Y1T,
    const ushort* __restrict__ Y2T, const ushort* __restrict__ wpT,
    const float* __restrict__ E, const float* __restrict__ bp,
    float* __restrict__ out)
{
    __shared__ ushort Alds[64][200];
    __shared__ ushort Wlds[64][200];
    __shared__ float  Elds[64][17];
    __shared__ float  bplds[16 * 64];

    const int r0 = blockIdx.x * 64;
    const int b  = r0 >> 12;
    const int n0 = r0 & (NN - 1);
    const int t  = threadIdx.x;
    const int w  = t >> 6;
    const int l  = t & 63;

    {
        float4 ev = *reinterpret_cast<const float4*>(E + (size_t)n0 * EMB + t * 4);
        int rr = t >> 2, dd = (t & 3) * 4;
        Elds[rr][dd + 0] = ev.x; Elds[rr][dd + 1] = ev.y;
        Elds[rr][dd + 2] = ev.z; Elds[rr][dd + 3] = ev.w;
        float4 bv = *reinterpret_cast<const float4*>(bp + t * 4);
        *reinterpret_cast<float4*>(&bplds[t * 4]) = bv;
    }
    {
        const int c  = t >> 2;
        const int mg = (t & 3) * 16;
        const size_t base = ((size_t)b * CIN + c) * NN + n0 + mg;
        const ushort* __restrict__ srcs[3] = {XT, Y1T, Y2T};
        #pragma unroll
        for (int ks = 0; ks < 3; ++ks) {
            short8v v0 = *reinterpret_cast<const short8v*>(srcs[ks] + base);
            short8v v1 = *reinterpret_cast<const short8v*>(srcs[ks] + base + 8);
            #pragma unroll
            for (int j = 0; j < 8; ++j) Alds[mg + j][ks * 64 + c] = (ushort)v0[j];
            #pragma unroll
            for (int j = 0; j < 8; ++j) Alds[mg + 8 + j][ks * 64 + c] = (ushort)v1[j];
        }
    }
    __syncthreads();

    const int rl = l & 15;
    const int kq = (l >> 4) * 8;

    short8v af[6];
    #pragma unroll
    for (int ks = 0; ks < 6; ++ks)
        af[ks] = *reinterpret_cast<const short8v*>(&Alds[w * 16 + rl][ks * 32 + kq]);

    f32x4 mainacc[4];
    #pragma unroll
    for (int ni = 0; ni < 4; ++ni) mainacc[ni] = (f32x4){0.f, 0.f, 0.f, 0.f};

    const int wo = t >> 2;
    const int wk = (t & 3) * 48;

    for (int d = 0; d < EMB; ++d) {
        __syncthreads();
        {
            const ushort* src = wpT + ((size_t)(d * 64 + wo)) * 192 + wk;
            #pragma unroll
            for (int j = 0; j < 6; ++j) {
                short8v v = *reinterpret_cast<const short8v*>(src + j * 8);
                *reinterpret_cast<short8v*>(&Wlds[wo][wk + j * 8]) = v;
            }
        }
        __syncthreads();

        f32x4 tmp[4];
        #pragma unroll
        for (int ni = 0; ni < 4; ++ni) tmp[ni] = (f32x4){0.f, 0.f, 0.f, 0.f};
        #pragma unroll
        for (int ks = 0; ks < 6; ++ks) {
            #pragma unroll
            for (int ni = 0; ni < 4; ++ni) {
                short8v bfr = *reinterpret_cast<const short8v*>(
                    &Wlds[ni * 16 + rl][ks * 32 + kq]);
                tmp[ni] = __builtin_amdgcn_mfma_f32_16x16x32_bf16(
                    af[ks], bfr, tmp[ni], 0, 0, 0);
            }
        }
        float e[4];
        #pragma unroll
        for (int j = 0; j < 4; ++j) e[j] = Elds[w * 16 + (l >> 4) * 4 + j][d];
        #pragma unroll
        for (int ni = 0; ni < 4; ++ni)
            #pragma unroll
            for (int j = 0; j < 4; ++j)
                mainacc[ni][j] += e[j] * tmp[ni][j];
    }

    const int lr4 = (l >> 4) * 4;
    #pragma unroll
    for (int ni = 0; ni < 4; ++ni) {
        int col = ni * 16 + rl;
        #pragma unroll
        for (int j = 0; j < 4; ++j) {
            int locrow = w * 16 + lr4 + j;
            float bias = 0.0f;
            #pragma unroll
            for (int d = 0; d < EMB; ++d)
                bias += Elds[locrow][d] * bplds[d * 64 + col];
            out[((size_t)b * NN + n0 + locrow) * COUT + col] = mainacc[ni][j] + bias;
        }
    }
}

// ---------------------------------------------------------------------------
extern "C" void kernel_launch(void* const* d_in, const int* in_sizes, int n_in,
                              void* d_out, int out_size, void* d_ws, size_t ws_size,
                              hipStream_t stream)
{
    const float* X  = (const float*)d_in[0];  // [16,4096,64]
    const float* E  = (const float*)d_in[1];  // [4096,16]
    const float* wp = (const float*)d_in[2];  // [16,3,64,64]
    const float* bp = (const float*)d_in[3];  // [16,64]
    float* out = (float*)d_out;

    char* ws = (char*)d_ws;
    size_t off = 0;
    ushort* Abf  = (ushort*)(ws + off); off += (size_t)NN * NN * 2;        // 32 MB
    ushort* XT   = (ushort*)(ws + off); off += (size_t)BB * CIN * NN * 2;  //  8 MB
    ushort* Y1T  = (ushort*)(ws + off); off += (size_t)BB * CIN * NN * 2;  //  8 MB
    ushort* Y2T  = (ushort*)(ws + off); off += (size_t)BB * CIN * NN * 2;  //  8 MB
    ushort* wpT  = (ushort*)(ws + off); off += (size_t)EMB * 64 * 192 * 2; // 384 KB
    off = (off + 255) & ~(size_t)255;
    float*  part = (float*)(ws + off);                                     // 32 MB

    const int NELEM_BLOCKS = (BB * CIN * NN) / (256 * 8);  // 2048

    adj_softmax_kernel    <<<NN, 256, 0, stream>>>(E, Abf);
    transpose_conv_kernel <<<dim3(NN / 64, BB), 256, 0, stream>>>(X, XT);
    wp_pack_kernel        <<<64, 256, 0, stream>>>(wp, wpT);
    gemm_mfma_splitk_kernel<<<1024, 256, 0, stream>>>(Abf, XT, part);
    combine_kernel        <<<NELEM_BLOCKS, 256, 0, stream>>>(part, XT, Y1T, 1.0f, 0);
    gemm_mfma_splitk_kernel<<<1024, 256, 0, stream>>>(Abf, Y1T, part);
    combine_kernel        <<<NELEM_BLOCKS, 256, 0, stream>>>(part, XT, Y2T, 2.0f, 1);
    apply_kernel          <<<1024, 256, 0, stream>>>(XT, Y1T, Y2T, wpT, E, bp, out);
}

// Round 7
// 267.121 us; speedup vs baseline: 2.0639x; 1.1273x over previous
//
#include <hip/hip_runtime.h>
#include <cstdint>

#define NN   4096
#define EMB  16
#define CIN  64
#define COUT 64
#define BB   16

typedef __attribute__((ext_vector_type(8))) short short8v;
typedef __attribute__((ext_vector_type(4))) float f32x4;

__device__ inline ushort f2bf(float f) {
    uint32_t u = __builtin_bit_cast(uint32_t, f);
    uint32_t r = (u + 0x7FFFu + ((u >> 16) & 1u)) >> 16;
    return (ushort)r;
}
__device__ inline float bf2f(ushort u) {
    uint32_t v = ((uint32_t)u) << 16;
    return __builtin_bit_cast(float, v);
}

// ---------------------------------------------------------------------------
// Kernel 1: A = softmax(relu(E @ E^T), axis=1), stored bf16.
// v2: block = 16 rows x 4096 cols, 256 threads. Thread (i=t>>5, j=t&31) owns
// rows {r0+i, r0+i+8} and strided cols {j+32*cc} per 128-col tile.
// E-col tiles staged in LDS [128][20] (stride-20 floats: lane-stride 20 ->
// ds_read_b128 at 4-cycle service floor). Row E-vecs hoisted to registers.
// Max-free two-pass softmax: relu=>s>=0, s<=~40 => exp(s) safe in f32;
// pass1 row-sums, pass2 recompute+write. Next tile's global loads issued
// before compute (latency hidden under FMA phase).
// ---------------------------------------------------------------------------
__global__ __launch_bounds__(256) void adj_softmax_kernel(
    const float* __restrict__ E, ushort* __restrict__ A)
{
    __shared__ float cl[128][20];

    const int r0 = blockIdx.x * 16;
    const int t  = threadIdx.x;
    const int i  = t >> 5;        // 0..7
    const int j  = t & 31;        // 0..31

    // hoist own-row E vectors (rows r0+i, r0+i+8)
    float er[2][16];
    #pragma unroll
    for (int rr = 0; rr < 2; ++rr) {
        const float4* ep = reinterpret_cast<const float4*>(
            E + (size_t)(r0 + i + rr * 8) * EMB);
        float4 a = ep[0], b = ep[1], c = ep[2], d = ep[3];
        er[rr][0]=a.x; er[rr][1]=a.y; er[rr][2]=a.z; er[rr][3]=a.w;
        er[rr][4]=b.x; er[rr][5]=b.y; er[rr][6]=b.z; er[rr][7]=b.w;
        er[rr][8]=c.x; er[rr][9]=c.y; er[rr][10]=c.z; er[rr][11]=c.w;
        er[rr][12]=d.x; er[rr][13]=d.y; er[rr][14]=d.z; er[rr][15]=d.w;
    }

    const int scol = t >> 1;         // staging col 0..127
    const int skh  = (t & 1) * 8;    // k-offset 0 or 8

    float rsum[2] = {0.0f, 0.0f};

    // ---------------- pass 1: row sums ----------------
    float4 v0, v1;
    {
        const float4* src = reinterpret_cast<const float4*>(
            E + (size_t)scol * EMB + skh);
        v0 = src[0]; v1 = src[1];
    }
    for (int g = 0; g < 32; ++g) {
        __syncthreads();   // previous tile's readers done
        *reinterpret_cast<float4*>(&cl[scol][skh])     = v0;
        *reinterpret_cast<float4*>(&cl[scol][skh + 4]) = v1;
        if (g < 31) {
            const float4* src = reinterpret_cast<const float4*>(
                E + (size_t)((g + 1) * 128 + scol) * EMB + skh);
            v0 = src[0]; v1 = src[1];
        }
        __syncthreads();   // tile staged
        #pragma unroll
        for (int cc = 0; cc < 4; ++cc) {
            const int c = j + 32 * cc;
            float4 e0 = *reinterpret_cast<const float4*>(&cl[c][0]);
            float4 e1 = *reinterpret_cast<const float4*>(&cl[c][4]);
            float4 e2 = *reinterpret_cast<const float4*>(&cl[c][8]);
            float4 e3 = *reinterpret_cast<const float4*>(&cl[c][12]);
            #pragma unroll
            for (int rr = 0; rr < 2; ++rr) {
                float s = er[rr][0]*e0.x + er[rr][1]*e0.y + er[rr][2]*e0.z  + er[rr][3]*e0.w
                        + er[rr][4]*e1.x + er[rr][5]*e1.y + er[rr][6]*e1.z  + er[rr][7]*e1.w
                        + er[rr][8]*e2.x + er[rr][9]*e2.y + er[rr][10]*e2.z + er[rr][11]*e2.w
                        + er[rr][12]*e3.x+ er[rr][13]*e3.y+ er[rr][14]*e3.z + er[rr][15]*e3.w;
                rsum[rr] += __expf(fmaxf(s, 0.0f));
            }
        }
    }
    // reduce across j (32 lanes; masks <=16 stay within the j-group)
    #pragma unroll
    for (int off = 16; off > 0; off >>= 1) {
        rsum[0] += __shfl_xor(rsum[0], off, 64);
        rsum[1] += __shfl_xor(rsum[1], off, 64);
    }
    const float inv0 = 1.0f / rsum[0];
    const float inv1 = 1.0f / rsum[1];

    // ---------------- pass 2: recompute + write ----------------
    {
        const float4* src = reinterpret_cast<const float4*>(
            E + (size_t)scol * EMB + skh);
        v0 = src[0]; v1 = src[1];
    }
    for (int g = 0; g < 32; ++g) {
        __syncthreads();
        *reinterpret_cast<float4*>(&cl[scol][skh])     = v0;
        *reinterpret_cast<float4*>(&cl[scol][skh + 4]) = v1;
        if (g < 31) {
            const float4* src = reinterpret_cast<const float4*>(
                E + (size_t)((g + 1) * 128 + scol) * EMB + skh);
            v0 = src[0]; v1 = src[1];
        }
        __syncthreads();
        #pragma unroll
        for (int cc = 0; cc < 4; ++cc) {
            const int c = j + 32 * cc;
            float4 e0 = *reinterpret_cast<const float4*>(&cl[c][0]);
            float4 e1 = *reinterpret_cast<const float4*>(&cl[c][4]);
            float4 e2 = *reinterpret_cast<const float4*>(&cl[c][8]);
            float4 e3 = *reinterpret_cast<const float4*>(&cl[c][12]);
            #pragma unroll
            for (int rr = 0; rr < 2; ++rr) {
                float s = er[rr][0]*e0.x + er[rr][1]*e0.y + er[rr][2]*e0.z  + er[rr][3]*e0.w
                        + er[rr][4]*e1.x + er[rr][5]*e1.y + er[rr][6]*e1.z  + er[rr][7]*e1.w
                        + er[rr][8]*e2.x + er[rr][9]*e2.y + er[rr][10]*e2.z + er[rr][11]*e2.w
                        + er[rr][12]*e3.x+ er[rr][13]*e3.y+ er[rr][14]*e3.z + er[rr][15]*e3.w;
                float v = __expf(fmaxf(s, 0.0f)) * (rr == 0 ? inv0 : inv1);
                A[(size_t)(r0 + i + rr * 8) * NN + g * 128 + c] = f2bf(v);
            }
        }
    }
}

// ---------------------------------------------------------------------------
// Kernel 2: XT[b][c][m] (bf16) = X[b][m][c] (f32) — transpose + convert.
// ---------------------------------------------------------------------------
__global__ __launch_bounds__(256) void transpose_conv_kernel(
    const float* __restrict__ X, ushort* __restrict__ XT)
{
    const int m0 = blockIdx.x * 64;
    const int b  = blockIdx.y;
    const int t  = threadIdx.x;
    __shared__ float tile[64][68];
    const float* Xb = X + (size_t)b * NN * CIN;

    #pragma unroll
    for (int it = 0; it < 4; ++it) {
        int r  = (t >> 4) + it * 16;
        int c4 = (t & 15) * 4;
        float4 v = *reinterpret_cast<const float4*>(Xb + (size_t)(m0 + r) * CIN + c4);
        *reinterpret_cast<float4*>(&tile[r][c4]) = v;
    }
    __syncthreads();
    #pragma unroll
    for (int it = 0; it < 2; ++it) {
        int c  = (t >> 3) + it * 32;
        int k8 = (t & 7) * 8;
        ushort4 p0, p1;
        p0.x = f2bf(tile[k8+0][c]); p0.y = f2bf(tile[k8+1][c]);
        p0.z = f2bf(tile[k8+2][c]); p0.w = f2bf(tile[k8+3][c]);
        p1.x = f2bf(tile[k8+4][c]); p1.y = f2bf(tile[k8+5][c]);
        p1.z = f2bf(tile[k8+6][c]); p1.w = f2bf(tile[k8+7][c]);
        ushort* dst = XT + ((size_t)b * CIN + c) * NN + m0 + k8;
        *reinterpret_cast<ushort4*>(dst)     = p0;
        *reinterpret_cast<ushort4*>(dst + 4) = p1;
    }
}

// ---------------------------------------------------------------------------
// Kernel 3: wpT[d][o][ki] (bf16) = wp[d][ki][o] (f32).  grid 64 x 256.
// ---------------------------------------------------------------------------
__global__ __launch_bounds__(256) void wp_pack_kernel(
    const float* __restrict__ wp, ushort* __restrict__ wpT)
{
    const int d  = blockIdx.x >> 2;
    const int q  = blockIdx.x & 3;
    const int o  = q * 16 + (threadIdx.x >> 4);
    const int k0 = (threadIdx.x & 15) * 12;
    const float* src = wp + (size_t)d * 12288 + o;
    ushort* dst = wpT + ((size_t)d * 64 + o) * 192 + k0;
    #pragma unroll
    for (int j = 0; j < 12; ++j) dst[j] = f2bf(src[(size_t)(k0 + j) * 64]);
}

// ---------------------------------------------------------------------------
// Kernel 4/5: MFMA GEMM, split-K x2 (1024 blocks, 4/CU).
// part[(s*BB+b)*CIN+c][m] = sum_{k in slice s} A[m,k]*BT[b,c,k]   (f32)
// ---------------------------------------------------------------------------
__global__ __launch_bounds__(256) void gemm_mfma_splitk_kernel(
    const ushort* __restrict__ A, const ushort* __restrict__ BT,
    float* __restrict__ part)
{
    __shared__ ushort Alds[128][72];
    __shared__ ushort Blds[64][72];

    const int i = blockIdx.x;                        // 0..1023
    const int base = i & 511;
    const int s = i >> 9;                            // k-slice 0/1
    const int m_tile = (base & 7) * 4 + ((base >> 3) & 3);
    const int b = base >> 5;
    const int n0 = m_tile * 128;
    const int t = threadIdx.x;
    const int w = t >> 6;
    const int l = t & 63;

    const ushort* Ab = A  + (size_t)n0 * NN;
    const ushort* Bb = BT + (size_t)b * CIN * NN;

    f32x4 acc[2][4];
    #pragma unroll
    for (int mi = 0; mi < 2; ++mi)
        #pragma unroll
        for (int ni = 0; ni < 4; ++ni)
            acc[mi][ni] = (f32x4){0.f, 0.f, 0.f, 0.f};

    const int arow = t >> 3;         // 0..31
    const int acol = (t & 7) * 8;
    const int xc   = t >> 2;         // 0..63
    const int xk   = (t & 3) * 16;

    const int k0 = s * (NN / 2);
    for (int kt = k0; kt < k0 + NN / 2; kt += 64) {
        #pragma unroll
        for (int it = 0; it < 4; ++it) {
            int r = arow + it * 32;
            uint4 v = *reinterpret_cast<const uint4*>(Ab + (size_t)r * NN + kt + acol);
            *reinterpret_cast<uint4*>(&Alds[r][acol]) = v;
        }
        {
            const ushort* src = Bb + (size_t)xc * NN + kt + xk;
            uint4 v0 = *reinterpret_cast<const uint4*>(src);
            uint4 v1 = *reinterpret_cast<const uint4*>(src + 8);
            *reinterpret_cast<uint4*>(&Blds[xc][xk])     = v0;
            *reinterpret_cast<uint4*>(&Blds[xc][xk + 8]) = v1;
        }
        __syncthreads();

        const int rl = l & 15;
        #pragma unroll
        for (int ks = 0; ks < 64; ks += 32) {
            const int koff = ks + (l >> 4) * 8;
            short8v af[2], bfr[4];
            #pragma unroll
            for (int mi = 0; mi < 2; ++mi)
                af[mi] = *reinterpret_cast<const short8v*>(&Alds[w * 32 + mi * 16 + rl][koff]);
            #pragma unroll
            for (int ni = 0; ni < 4; ++ni)
                bfr[ni] = *reinterpret_cast<const short8v*>(&Blds[ni * 16 + rl][koff]);
            #pragma unroll
            for (int mi = 0; mi < 2; ++mi)
                #pragma unroll
                for (int ni = 0; ni < 4; ++ni)
                    acc[mi][ni] = __builtin_amdgcn_mfma_f32_16x16x32_bf16(
                        af[mi], bfr[ni], acc[mi][ni], 0, 0, 0);
        }
        __syncthreads();
    }

    const int rl = l & 15;
    const int rquad = (l >> 4) * 4;
    #pragma unroll
    for (int mi = 0; mi < 2; ++mi) {
        int row0 = w * 32 + mi * 16 + rquad;
        #pragma unroll
        for (int ni = 0; ni < 4; ++ni) {
            int c = ni * 16 + rl;
            float4 pk = make_float4(acc[mi][ni][0], acc[mi][ni][1],
                                    acc[mi][ni][2], acc[mi][ni][3]);
            *reinterpret_cast<float4*>(
                part + ((size_t)(s * BB + b) * CIN + c) * NN + n0 + row0) = pk;
        }
    }
}

// ---------------------------------------------------------------------------
// Kernel 6: combine split-K partials + epilogue.
// ---------------------------------------------------------------------------
__global__ __launch_bounds__(256) void combine_kernel(
    const float* __restrict__ part, const ushort* __restrict__ XT,
    ushort* __restrict__ Yt, float alpha, int dosub)
{
    const size_t idx = ((size_t)blockIdx.x * 256 + threadIdx.x) * 8;
    const size_t half = (size_t)BB * CIN * NN;
    float4 a0 = *reinterpret_cast<const float4*>(part + idx);
    float4 a1 = *reinterpret_cast<const float4*>(part + idx + 4);
    float4 b0 = *reinterpret_cast<const float4*>(part + half + idx);
    float4 b1 = *reinterpret_cast<const float4*>(part + half + idx + 4);
    float r[8] = { alpha*(a0.x+b0.x), alpha*(a0.y+b0.y),
                   alpha*(a0.z+b0.z), alpha*(a0.w+b0.w),
                   alpha*(a1.x+b1.x), alpha*(a1.y+b1.y),
                   alpha*(a1.z+b1.z), alpha*(a1.w+b1.w) };
    if (dosub) {
        short8v xv = *reinterpret_cast<const short8v*>(XT + idx);
        #pragma unroll
        for (int j = 0; j < 8; ++j) r[j] -= bf2f((ushort)xv[j]);
    }
    short8v o;
    #pragma unroll
    for (int j = 0; j < 8; ++j) o[j] = (short)f2bf(r[j]);
    *reinterpret_cast<short8v*>(Yt + idx) = o;
}

// ---------------------------------------------------------------------------
// Kernel 7: apply.  out[b,n,o] = sum_d E[n,d]*( XG[b,n,:]@wpT[d] + bp[d,o] )
// ---------------------------------------------------------------------------
__global__ __launch_bounds__(256) void apply_kernel(
    const ushort* __restrict__ XT, const ushort* __restrict__ Y1T,
    const ushort* __restrict__ Y2T, const ushort* __restrict__ wpT,
    const float* __restrict__ E, const float* __restrict__ bp,
    float* __restrict__ out)
{
    __shared__ ushort Alds[64][200];
    __shared__ ushort Wlds[64][200];
    __shared__ float  Elds[64][17];
    __shared__ float  bplds[16 * 64];

    const int r0 = blockIdx.x * 64;
    const int b  = r0 >> 12;
    const int n0 = r0 & (NN - 1);
    const int t  = threadIdx.x;
    const int w  = t >> 6;
    const int l  = t & 63;

    {
        float4 ev = *reinterpret_cast<const float4*>(E + (size_t)n0 * EMB + t * 4);
        int rr = t >> 2, dd = (t & 3) * 4;
        Elds[rr][dd + 0] = ev.x; Elds[rr][dd + 1] = ev.y;
        Elds[rr][dd + 2] = ev.z; Elds[rr][dd + 3] = ev.w;
        float4 bv = *reinterpret_cast<const float4*>(bp + t * 4);
        *reinterpret_cast<float4*>(&bplds[t * 4]) = bv;
    }
    {
        const int c  = t >> 2;
        const int mg = (t & 3) * 16;
        const size_t base = ((size_t)b * CIN + c) * NN + n0 + mg;
        const ushort* __restrict__ srcs[3] = {XT, Y1T, Y2T};
        #pragma unroll
        for (int ks = 0; ks < 3; ++ks) {
            short8v v0 = *reinterpret_cast<const short8v*>(srcs[ks] + base);
            short8v v1 = *reinterpret_cast<const short8v*>(srcs[ks] + base + 8);
            #pragma unroll
            for (int j = 0; j < 8; ++j) Alds[mg + j][ks * 64 + c] = (ushort)v0[j];
            #pragma unroll
            for (int j = 0; j < 8; ++j) Alds[mg + 8 + j][ks * 64 + c] = (ushort)v1[j];
        }
    }
    __syncthreads();

    const int rl = l & 15;
    const int kq = (l >> 4) * 8;

    short8v af[6];
    #pragma unroll
    for (int ks = 0; ks < 6; ++ks)
        af[ks] = *reinterpret_cast<const short8v*>(&Alds[w * 16 + rl][ks * 32 + kq]);

    f32x4 mainacc[4];
    #pragma unroll
    for (int ni = 0; ni < 4; ++ni) mainacc[ni] = (f32x4){0.f, 0.f, 0.f, 0.f};

    const int wo = t >> 2;
    const int wk = (t & 3) * 48;

    for (int d = 0; d < EMB; ++d) {
        __syncthreads();
        {
            const ushort* src = wpT + ((size_t)(d * 64 + wo)) * 192 + wk;
            #pragma unroll
            for (int j = 0; j < 6; ++j) {
                short8v v = *reinterpret_cast<const short8v*>(src + j * 8);
                *reinterpret_cast<short8v*>(&Wlds[wo][wk + j * 8]) = v;
            }
        }
        __syncthreads();

        f32x4 tmp[4];
        #pragma unroll
        for (int ni = 0; ni < 4; ++ni) tmp[ni] = (f32x4){0.f, 0.f, 0.f, 0.f};
        #pragma unroll
        for (int ks = 0; ks < 6; ++ks) {
            #pragma unroll
            for (int ni = 0; ni < 4; ++ni) {
                short8v bfr = *reinterpret_cast<const short8v*>(
                    &Wlds[ni * 16 + rl][ks * 32 + kq]);
                tmp[ni] = __builtin_amdgcn_mfma_f32_16x16x32_bf16(
                    af[ks], bfr, tmp[ni], 0, 0, 0);
            }
        }
        float e[4];
        #pragma unroll
        for (int j = 0; j < 4; ++j) e[j] = Elds[w * 16 + (l >> 4) * 4 + j][d];
        #pragma unroll
        for (int ni = 0; ni < 4; ++ni)
            #pragma unroll
            for (int j = 0; j < 4; ++j)
                mainacc[ni][j] += e[j] * tmp[ni][j];
    }

    const int lr4 = (l >> 4) * 4;
    #pragma unroll
    for (int ni = 0; ni < 4; ++ni) {
        int col = ni * 16 + rl;
        #pragma unroll
        for (int j = 0; j < 4; ++j) {
            int locrow = w * 16 + lr4 + j;
            float bias = 0.0f;
            #pragma unroll
            for (int d = 0; d < EMB; ++d)
                bias += Elds[locrow][d] * bplds[d * 64 + col];
            out[((size_t)b * NN + n0 + locrow) * COUT + col] = mainacc[ni][j] + bias;
        }
    }
}

// ---------------------------------------------------------------------------
extern "C" void kernel_launch(void* const* d_in, const int* in_sizes, int n_in,
                              void* d_out, int out_size, void* d_ws, size_t ws_size,
                              hipStream_t stream)
{
    const float* X  = (const float*)d_in[0];  // [16,4096,64]
    const float* E  = (const float*)d_in[1];  // [4096,16]
    const float* wp = (const float*)d_in[2];  // [16,3,64,64]
    const float* bp = (const float*)d_in[3];  // [16,64]
    float* out = (float*)d_out;

    char* ws = (char*)d_ws;
    size_t off = 0;
    ushort* Abf  = (ushort*)(ws + off); off += (size_t)NN * NN * 2;        // 32 MB
    ushort* XT   = (ushort*)(ws + off); off += (size_t)BB * CIN * NN * 2;  //  8 MB
    ushort* Y1T  = (ushort*)(ws + off); off += (size_t)BB * CIN * NN * 2;  //  8 MB
    ushort* Y2T  = (ushort*)(ws + off); off += (size_t)BB * CIN * NN * 2;  //  8 MB
    ushort* wpT  = (ushort*)(ws + off); off += (size_t)EMB * 64 * 192 * 2; // 384 KB
    off = (off + 255) & ~(size_t)255;
    float*  part = (float*)(ws + off);                                     // 32 MB

    const int NELEM_BLOCKS = (BB * CIN * NN) / (256 * 8);  // 2048

    adj_softmax_kernel    <<<NN / 16, 256, 0, stream>>>(E, Abf);
    transpose_conv_kernel <<<dim3(NN / 64, BB), 256, 0, stream>>>(X, XT);
    wp_pack_kernel        <<<64, 256, 0, stream>>>(wp, wpT);
    gemm_mfma_splitk_kernel<<<1024, 256, 0, stream>>>(Abf, XT, part);
    combine_kernel        <<<NELEM_BLOCKS, 256, 0, stream>>>(part, XT, Y1T, 1.0f, 0);
    gemm_mfma_splitk_kernel<<<1024, 256, 0, stream>>>(Abf, Y1T, part);
    combine_kernel        <<<NELEM_BLOCKS, 256, 0, stream>>>(part, XT, Y2T, 2.0f, 1);
    apply_kernel          <<<1024, 256, 0, stream>>>(XT, Y1T, Y2T, wpT, E, bp, out);
}

// Round 8
// 230.954 us; speedup vs baseline: 2.3871x; 1.1566x over previous
//
#include <hip/hip_runtime.h>
#include <cstdint>

#define NN   4096
#define EMB  16
#define CIN  64
#define COUT 64
#define BB   16

typedef __attribute__((ext_vector_type(8))) short short8v;
typedef __attribute__((ext_vector_type(4))) float f32x4;

__device__ inline ushort f2bf(float f) {
    uint32_t u = __builtin_bit_cast(uint32_t, f);
    uint32_t r = (u + 0x7FFFu + ((u >> 16) & 1u)) >> 16;
    return (ushort)r;
}
__device__ inline float bf2f(ushort u) {
    uint32_t v = ((uint32_t)u) << 16;
    return __builtin_bit_cast(float, v);
}
// async global->LDS, 16B per lane. LDS dest = wave-uniform base + lane*16.
__device__ inline void gload_lds16(const ushort* g, ushort* l) {
    __builtin_amdgcn_global_load_lds(
        (const __attribute__((address_space(1))) void*)g,
        (__attribute__((address_space(3))) void*)l, 16, 0, 0);
}

// ---------------------------------------------------------------------------
// Kernel 1: A = softmax(relu(E @ E^T), axis=1), stored bf16.
// Block = 16 rows x 4096 cols; LDS col-staging; max-free two-pass softmax.
// ---------------------------------------------------------------------------
__global__ __launch_bounds__(256) void adj_softmax_kernel(
    const float* __restrict__ E, ushort* __restrict__ A)
{
    __shared__ float cl[128][20];

    const int r0 = blockIdx.x * 16;
    const int t  = threadIdx.x;
    const int i  = t >> 5;        // 0..7
    const int j  = t & 31;        // 0..31

    float er[2][16];
    #pragma unroll
    for (int rr = 0; rr < 2; ++rr) {
        const float4* ep = reinterpret_cast<const float4*>(
            E + (size_t)(r0 + i + rr * 8) * EMB);
        float4 a = ep[0], b = ep[1], c = ep[2], d = ep[3];
        er[rr][0]=a.x; er[rr][1]=a.y; er[rr][2]=a.z; er[rr][3]=a.w;
        er[rr][4]=b.x; er[rr][5]=b.y; er[rr][6]=b.z; er[rr][7]=b.w;
        er[rr][8]=c.x; er[rr][9]=c.y; er[rr][10]=c.z; er[rr][11]=c.w;
        er[rr][12]=d.x; er[rr][13]=d.y; er[rr][14]=d.z; er[rr][15]=d.w;
    }

    const int scol = t >> 1;
    const int skh  = (t & 1) * 8;

    float rsum[2] = {0.0f, 0.0f};

    float4 v0, v1;
    {
        const float4* src = reinterpret_cast<const float4*>(
            E + (size_t)scol * EMB + skh);
        v0 = src[0]; v1 = src[1];
    }
    for (int g = 0; g < 32; ++g) {
        __syncthreads();
        *reinterpret_cast<float4*>(&cl[scol][skh])     = v0;
        *reinterpret_cast<float4*>(&cl[scol][skh + 4]) = v1;
        if (g < 31) {
            const float4* src = reinterpret_cast<const float4*>(
                E + (size_t)((g + 1) * 128 + scol) * EMB + skh);
            v0 = src[0]; v1 = src[1];
        }
        __syncthreads();
        #pragma unroll
        for (int cc = 0; cc < 4; ++cc) {
            const int c = j + 32 * cc;
            float4 e0 = *reinterpret_cast<const float4*>(&cl[c][0]);
            float4 e1 = *reinterpret_cast<const float4*>(&cl[c][4]);
            float4 e2 = *reinterpret_cast<const float4*>(&cl[c][8]);
            float4 e3 = *reinterpret_cast<const float4*>(&cl[c][12]);
            #pragma unroll
            for (int rr = 0; rr < 2; ++rr) {
                float s = er[rr][0]*e0.x + er[rr][1]*e0.y + er[rr][2]*e0.z  + er[rr][3]*e0.w
                        + er[rr][4]*e1.x + er[rr][5]*e1.y + er[rr][6]*e1.z  + er[rr][7]*e1.w
                        + er[rr][8]*e2.x + er[rr][9]*e2.y + er[rr][10]*e2.z + er[rr][11]*e2.w
                        + er[rr][12]*e3.x+ er[rr][13]*e3.y+ er[rr][14]*e3.z + er[rr][15]*e3.w;
                rsum[rr] += __expf(fmaxf(s, 0.0f));
            }
        }
    }
    #pragma unroll
    for (int off = 16; off > 0; off >>= 1) {
        rsum[0] += __shfl_xor(rsum[0], off, 64);
        rsum[1] += __shfl_xor(rsum[1], off, 64);
    }
    const float inv0 = 1.0f / rsum[0];
    const float inv1 = 1.0f / rsum[1];

    {
        const float4* src = reinterpret_cast<const float4*>(
            E + (size_t)scol * EMB + skh);
        v0 = src[0]; v1 = src[1];
    }
    for (int g = 0; g < 32; ++g) {
        __syncthreads();
        *reinterpret_cast<float4*>(&cl[scol][skh])     = v0;
        *reinterpret_cast<float4*>(&cl[scol][skh + 4]) = v1;
        if (g < 31) {
            const float4* src = reinterpret_cast<const float4*>(
                E + (size_t)((g + 1) * 128 + scol) * EMB + skh);
            v0 = src[0]; v1 = src[1];
        }
        __syncthreads();
        #pragma unroll
        for (int cc = 0; cc < 4; ++cc) {
            const int c = j + 32 * cc;
            float4 e0 = *reinterpret_cast<const float4*>(&cl[c][0]);
            float4 e1 = *reinterpret_cast<const float4*>(&cl[c][4]);
            float4 e2 = *reinterpret_cast<const float4*>(&cl[c][8]);
            float4 e3 = *reinterpret_cast<const float4*>(&cl[c][12]);
            #pragma unroll
            for (int rr = 0; rr < 2; ++rr) {
                float s = er[rr][0]*e0.x + er[rr][1]*e0.y + er[rr][2]*e0.z  + er[rr][3]*e0.w
                        + er[rr][4]*e1.x + er[rr][5]*e1.y + er[rr][6]*e1.z  + er[rr][7]*e1.w
                        + er[rr][8]*e2.x + er[rr][9]*e2.y + er[rr][10]*e2.z + er[rr][11]*e2.w
                        + er[rr][12]*e3.x+ er[rr][13]*e3.y+ er[rr][14]*e3.z + er[rr][15]*e3.w;
                float v = __expf(fmaxf(s, 0.0f)) * (rr == 0 ? inv0 : inv1);
                A[(size_t)(r0 + i + rr * 8) * NN + g * 128 + c] = f2bf(v);
            }
        }
    }
}

// ---------------------------------------------------------------------------
// Kernel 2: XT[b][c][m] (bf16) = X[b][m][c] (f32) — transpose + convert.
// ---------------------------------------------------------------------------
__global__ __launch_bounds__(256) void transpose_conv_kernel(
    const float* __restrict__ X, ushort* __restrict__ XT)
{
    const int m0 = blockIdx.x * 64;
    const int b  = blockIdx.y;
    const int t  = threadIdx.x;
    __shared__ float tile[64][68];
    const float* Xb = X + (size_t)b * NN * CIN;

    #pragma unroll
    for (int it = 0; it < 4; ++it) {
        int r  = (t >> 4) + it * 16;
        int c4 = (t & 15) * 4;
        float4 v = *reinterpret_cast<const float4*>(Xb + (size_t)(m0 + r) * CIN + c4);
        *reinterpret_cast<float4*>(&tile[r][c4]) = v;
    }
    __syncthreads();
    #pragma unroll
    for (int it = 0; it < 2; ++it) {
        int c  = (t >> 3) + it * 32;
        int k8 = (t & 7) * 8;
        ushort4 p0, p1;
        p0.x = f2bf(tile[k8+0][c]); p0.y = f2bf(tile[k8+1][c]);
        p0.z = f2bf(tile[k8+2][c]); p0.w = f2bf(tile[k8+3][c]);
        p1.x = f2bf(tile[k8+4][c]); p1.y = f2bf(tile[k8+5][c]);
        p1.z = f2bf(tile[k8+6][c]); p1.w = f2bf(tile[k8+7][c]);
        ushort* dst = XT + ((size_t)b * CIN + c) * NN + m0 + k8;
        *reinterpret_cast<ushort4*>(dst)     = p0;
        *reinterpret_cast<ushort4*>(dst + 4) = p1;
    }
}

// ---------------------------------------------------------------------------
// Kernel 3: wpT[d][o][ki] (bf16) = wp[d][ki][o] (f32).  grid 64 x 256.
// ---------------------------------------------------------------------------
__global__ __launch_bounds__(256) void wp_pack_kernel(
    const float* __restrict__ wp, ushort* __restrict__ wpT)
{
    const int d  = blockIdx.x >> 2;
    const int q  = blockIdx.x & 3;
    const int o  = q * 16 + (threadIdx.x >> 4);
    const int k0 = (threadIdx.x & 15) * 12;
    const float* src = wp + (size_t)d * 12288 + o;
    ushort* dst = wpT + ((size_t)d * 64 + o) * 192 + k0;
    #pragma unroll
    for (int j = 0; j < 12; ++j) dst[j] = f2bf(src[(size_t)(k0 + j) * 64]);
}

// ---------------------------------------------------------------------------
// Kernel 4/5: merged MFMA GEMM (m97 structure).
// C[4096 m, 1024 c'] = A[4096,4096] @ BT[c'][k]^T, c' = b*64+c.
// BM=128, BN=128, BK=64, 4 waves of 64x64 (4x4 frags of 16x16x32).
// Staging: global_load_lds width=16 into LINEAR LDS [128][64]; bank fix via
// XOR swizzle pair (m201): source chunk ^= (row&7) at load, read chunk
// ^= (row&7) at ds_read_b128 -> all rows' chunks spread over 32 banks.
// Split-K x4: slice s covers k in [s*1024, s*1024+1024). Partials bf16.
// Grid 1024: bid -> n=bid&7 (XCD-pinned B panel), m=(bid>>3)&31, s=bid>>8.
// ---------------------------------------------------------------------------
__global__ __launch_bounds__(256) void gemm_merged_kernel(
    const ushort* __restrict__ A, const ushort* __restrict__ BT,
    ushort* __restrict__ part)
{
    __shared__ ushort Alds[128 * 64];
    __shared__ ushort Blds[128 * 64];

    const int bid = blockIdx.x;
    const int n   = bid & 7;
    const int m   = (bid >> 3) & 31;
    const int s   = bid >> 8;
    const int m0  = m * 128;
    const int c0  = n * 128;
    const int k0  = s * 1024;

    const int t = threadIdx.x;
    const int w = t >> 6;
    const int l = t & 63;

    const ushort* Ag = A  + (size_t)m0 * NN;
    const ushort* Bg = BT + (size_t)c0 * NN;

    // staging geometry: instr ii (0..15 per matrix) covers rows ii*8..ii*8+7;
    // lane covers row ii*8 + (l>>3), chunk (l&7), with source chunk XOR (row&7).
    const int srow = l >> 3;            // 0..7
    const int sch  = l & 7;             // 0..7

    f32x4 acc[4][4];
    #pragma unroll
    for (int mi = 0; mi < 4; ++mi)
        #pragma unroll
        for (int ni = 0; ni < 4; ++ni)
            acc[mi][ni] = (f32x4){0.f, 0.f, 0.f, 0.f};

    const int rl  = l & 15;
    const int hi  = l >> 4;
    const int wr  = w >> 1;             // 0..1
    const int wc  = w & 1;              // 0..1
    const int rsw = rl & 7;             // read-side swizzle key

    for (int kt = 0; kt < 16; ++kt) {
        const int ko = k0 + kt * 64;
        #pragma unroll
        for (int i = 0; i < 4; ++i) {
            const int ii = (w << 2) + i;       // 0..15 (wave-uniform)
            const int r  = (ii << 3) + srow;   // 0..127
            const int ch = sch ^ (r & 7);
            gload_lds16(Ag + (size_t)r * NN + ko + (ch << 3), &Alds[ii << 9]);
            gload_lds16(Bg + (size_t)r * NN + ko + (ch << 3), &Blds[ii << 9]);
        }
        __syncthreads();   // drains vmcnt(0) then barrier

        #pragma unroll
        for (int ks = 0; ks < 2; ++ks) {
            const int cb = (ks << 2) + hi;     // chunk base 0..7
            const int cx = (cb ^ rsw) << 3;
            short8v af[4], bf[4];
            #pragma unroll
            for (int mi = 0; mi < 4; ++mi) {
                const int R = wr * 64 + mi * 16 + rl;
                af[mi] = *reinterpret_cast<const short8v*>(&Alds[(R << 6) + cx]);
            }
            #pragma unroll
            for (int ni = 0; ni < 4; ++ni) {
                const int R = wc * 64 + ni * 16 + rl;
                bf[ni] = *reinterpret_cast<const short8v*>(&Blds[(R << 6) + cx]);
            }
            #pragma unroll
            for (int mi = 0; mi < 4; ++mi)
                #pragma unroll
                for (int ni = 0; ni < 4; ++ni)
                    acc[mi][ni] = __builtin_amdgcn_mfma_f32_16x16x32_bf16(
                        af[mi], bf[ni], acc[mi][ni], 0, 0, 0);
        }
        __syncthreads();
    }

    // Epilogue: bf16 partial, part[s][c'][m].  C/D: col=lane&15, row=quad*4+j.
    ushort* ps = part + (size_t)s * 1024 * NN;
    #pragma unroll
    for (int mi = 0; mi < 4; ++mi) {
        const int mrow = m0 + wr * 64 + mi * 16 + hi * 4;
        #pragma unroll
        for (int ni = 0; ni < 4; ++ni) {
            const int cp = c0 + wc * 64 + ni * 16 + rl;
            ushort4 pk;
            pk.x = f2bf(acc[mi][ni][0]); pk.y = f2bf(acc[mi][ni][1]);
            pk.z = f2bf(acc[mi][ni][2]); pk.w = f2bf(acc[mi][ni][3]);
            *reinterpret_cast<ushort4*>(ps + (size_t)cp * NN + mrow) = pk;
        }
    }
}

// ---------------------------------------------------------------------------
// Kernel 6: combine 4 bf16 split-K partials + epilogue.
// Yt[c'][m] = f2bf( alpha*(p0+p1+p2+p3) - (dosub ? XT : 0) )
// ---------------------------------------------------------------------------
__global__ __launch_bounds__(256) void combine_kernel(
    const ushort* __restrict__ part, const ushort* __restrict__ XT,
    ushort* __restrict__ Yt, float alpha, int dosub)
{
    const size_t idx = ((size_t)blockIdx.x * 256 + threadIdx.x) * 8;
    const size_t S = (size_t)1024 * NN;
    short8v p0 = *reinterpret_cast<const short8v*>(part + idx);
    short8v p1 = *reinterpret_cast<const short8v*>(part + S + idx);
    short8v p2 = *reinterpret_cast<const short8v*>(part + 2 * S + idx);
    short8v p3 = *reinterpret_cast<const short8v*>(part + 3 * S + idx);
    float r[8];
    #pragma unroll
    for (int j = 0; j < 8; ++j)
        r[j] = alpha * (bf2f((ushort)p0[j]) + bf2f((ushort)p1[j])
                      + bf2f((ushort)p2[j]) + bf2f((ushort)p3[j]));
    if (dosub) {
        short8v xv = *reinterpret_cast<const short8v*>(XT + idx);
        #pragma unroll
        for (int j = 0; j < 8; ++j) r[j] -= bf2f((ushort)xv[j]);
    }
    short8v o;
    #pragma unroll
    for (int j = 0; j < 8; ++j) o[j] = (short)f2bf(r[j]);
    *reinterpret_cast<short8v*>(Yt + idx) = o;
}

// ---------------------------------------------------------------------------
// Kernel 7: apply.  out[b,n,o] = sum_d E[n,d]*( XG[b,n,:]@wpT[d] + bp[d,o] )
// ---------------------------------------------------------------------------
__global__ __launch_bounds__(256) void apply_kernel(
    const ushort* __restrict__ XT, const ushort* __restrict__ Y1T,
    const ushort* __restrict__ Y2T, const ushort* __restrict__ wpT,
    const float* __restrict__ E, const float* __restrict__ bp,
    float* __restrict__ out)
{
    __shared__ ushort Alds[64][200];
    __shared__ ushort Wlds[64][200];
    __shared__ float  Elds[64][17];
    __shared__ float  bplds[16 * 64];

    const int r0 = blockIdx.x * 64;
    const int b  = r0 >> 12;
    const int n0 = r0 & (NN - 1);
    const int t  = threadIdx.x;
    const int w  = t >> 6;
    const int l  = t & 63;

    {
        float4 ev = *reinterpret_cast<const float4*>(E + (size_t)n0 * EMB + t * 4);
        int rr = t >> 2, dd = (t & 3) * 4;
        Elds[rr][dd + 0] = ev.x; Elds[rr][dd + 1] = ev.y;
        Elds[rr][dd + 2] = ev.z; Elds[rr][dd + 3] = ev.w;
        float4 bv = *reinterpret_cast<const float4*>(bp + t * 4);
        *reinterpret_cast<float4*>(&bplds[t * 4]) = bv;
    }
    {
        const int c  = t >> 2;
        const int mg = (t & 3) * 16;
        const size_t base = ((size_t)b * CIN + c) * NN + n0 + mg;
        const ushort* __restrict__ srcs[3] = {XT, Y1T, Y2T};
        #pragma unroll
        for (int ks = 0; ks < 3; ++ks) {
            short8v v0 = *reinterpret_cast<const short8v*>(srcs[ks] + base);
            short8v v1 = *reinterpret_cast<const short8v*>(srcs[ks] + base + 8);
            #pragma unroll
            for (int j = 0; j < 8; ++j) Alds[mg + j][ks * 64 + c] = (ushort)v0[j];
            #pragma unroll
            for (int j = 0; j < 8; ++j) Alds[mg + 8 + j][ks * 64 + c] = (ushort)v1[j];
        }
    }
    __syncthreads();

    const int rl = l & 15;
    const int kq = (l >> 4) * 8;

    short8v af[6];
    #pragma unroll
    for (int ks = 0; ks < 6; ++ks)
        af[ks] = *reinterpret_cast<const short8v*>(&Alds[w * 16 + rl][ks * 32 + kq]);

    f32x4 mainacc[4];
    #pragma unroll
    for (int ni = 0; ni < 4; ++ni) mainacc[ni] = (f32x4){0.f, 0.f, 0.f, 0.f};

    const int wo = t >> 2;
    const int wk = (t & 3) * 48;

    for (int d = 0; d < EMB; ++d) {
        __syncthreads();
        {
            const ushort* src = wpT + ((size_t)(d * 64 + wo)) * 192 + wk;
            #pragma unroll
            for (int j = 0; j < 6; ++j) {
                short8v v = *reinterpret_cast<const short8v*>(src + j * 8);
                *reinterpret_cast<short8v*>(&Wlds[wo][wk + j * 8]) = v;
            }
        }
        __syncthreads();

        f32x4 tmp[4];
        #pragma unroll
        for (int ni = 0; ni < 4; ++ni) tmp[ni] = (f32x4){0.f, 0.f, 0.f, 0.f};
        #pragma unroll
        for (int ks = 0; ks < 6; ++ks) {
            #pragma unroll
            for (int ni = 0; ni < 4; ++ni) {
                short8v bfr = *reinterpret_cast<const short8v*>(
                    &Wlds[ni * 16 + rl][ks * 32 + kq]);
                tmp[ni] = __builtin_amdgcn_mfma_f32_16x16x32_bf16(
                    af[ks], bfr, tmp[ni], 0, 0, 0);
            }
        }
        float e[4];
        #pragma unroll
        for (int j = 0; j < 4; ++j) e[j] = Elds[w * 16 + (l >> 4) * 4 + j][d];
        #pragma unroll
        for (int ni = 0; ni < 4; ++ni)
            #pragma unroll
            for (int j = 0; j < 4; ++j)
                mainacc[ni][j] += e[j] * tmp[ni][j];
    }

    const int lr4 = (l >> 4) * 4;
    #pragma unroll
    for (int ni = 0; ni < 4; ++ni) {
        int col = ni * 16 + rl;
        #pragma unroll
        for (int j = 0; j < 4; ++j) {
            int locrow = w * 16 + lr4 + j;
            float bias = 0.0f;
            #pragma unroll
            for (int d = 0; d < EMB; ++d)
                bias += Elds[locrow][d] * bplds[d * 64 + col];
            out[((size_t)b * NN + n0 + locrow) * COUT + col] = mainacc[ni][j] + bias;
        }
    }
}

// ---------------------------------------------------------------------------
extern "C" void kernel_launch(void* const* d_in, const int* in_sizes, int n_in,
                              void* d_out, int out_size, void* d_ws, size_t ws_size,
                              hipStream_t stream)
{
    const float* X  = (const float*)d_in[0];  // [16,4096,64]
    const float* E  = (const float*)d_in[1];  // [4096,16]
    const float* wp = (const float*)d_in[2];  // [16,3,64,64]
    const float* bp = (const float*)d_in[3];  // [16,64]
    float* out = (float*)d_out;

    char* ws = (char*)d_ws;
    size_t off = 0;
    ushort* Abf  = (ushort*)(ws + off); off += (size_t)NN * NN * 2;        // 32 MB
    ushort* XT   = (ushort*)(ws + off); off += (size_t)BB * CIN * NN * 2;  //  8 MB
    ushort* Y1T  = (ushort*)(ws + off); off += (size_t)BB * CIN * NN * 2;  //  8 MB
    ushort* Y2T  = (ushort*)(ws + off); off += (size_t)BB * CIN * NN * 2;  //  8 MB
    ushort* wpT  = (ushort*)(ws + off); off += (size_t)EMB * 64 * 192 * 2; // 384 KB
    off = (off + 255) & ~(size_t)255;
    ushort* part = (ushort*)(ws + off);  // 4 x 1024 x 4096 bf16 = 33.5 MB

    const int NELEM_BLOCKS = (BB * CIN * NN) / (256 * 8);  // 2048

    adj_softmax_kernel    <<<NN / 16, 256, 0, stream>>>(E, Abf);
    transpose_conv_kernel <<<dim3(NN / 64, BB), 256, 0, stream>>>(X, XT);
    wp_pack_kernel        <<<64, 256, 0, stream>>>(wp, wpT);
    gemm_merged_kernel    <<<1024, 256, 0, stream>>>(Abf, XT, part);
    combine_kernel        <<<NELEM_BLOCKS, 256, 0, stream>>>(part, XT, Y1T, 1.0f, 0);
    gemm_merged_kernel    <<<1024, 256, 0, stream>>>(Abf, Y1T, part);
    combine_kernel        <<<NELEM_BLOCKS, 256, 0, stream>>>(part, XT, Y2T, 2.0f, 1);
    apply_kernel          <<<1024, 256, 0, stream>>>(XT, Y1T, Y2T, wpT, E, bp, out);
}